// Round 8
// baseline (328.379 us; speedup 1.0000x reference)
//
#include <hip/hip_runtime.h>
#include <math.h>

namespace {

constexpr int NF   = 256;   // n_feature / tokens
constexpr int EH   = 128;   // embedder hidden
constexpr int E    = 64;    // embedded dim
constexpr int EPS  = 33;    // per-half emb row stride (odd => conflict-free)
constexpr int EHI  = 8448;  // emb hi-half base offset in big (256*33)
constexpr int KS   = 16;    // k's per h tile
constexpr int H    = 64;    // lstm size
constexpr int SHD  = 256;   // shared hidden
constexpr int SD   = 128;   // shared dim
constexpr int NA   = 257;   // n_action
constexpr int NSHUF = 4;

__device__ __forceinline__ float fsig(float x) {
  return 1.f / (1.f + __expf(-x));
}
__device__ __forceinline__ float ftanh(float x) {
  return 1.f - 2.f / (__expf(2.f * x) + 1.f);
}
__device__ __forceinline__ float4 f4ma(float s, const float4 w, float4 a) {
  a.x = fmaf(s, w.x, a.x); a.y = fmaf(s, w.y, a.y);
  a.z = fmaf(s, w.z, a.z); a.w = fmaf(s, w.w, a.w);
  return a;
}

// r7 lesson: 32 accs + staging temps > 64-VGPR budget -> scratch. This round:
// 16 accs (4 tok x 4 col), two col-half passes, h recomputed per pass.
__global__ __launch_bounds__(512)
__attribute__((amdgpu_waves_per_eu(4)))
void seqnet(
    const float* __restrict__ state, const int* __restrict__ acquired,
    const float* __restrict__ We1, const float* __restrict__ be1,
    const float* __restrict__ We2, const float* __restrict__ be2,
    const float* __restrict__ Wih, const float* __restrict__ Whh,
    const float* __restrict__ bih, const float* __restrict__ bhh,
    const float* __restrict__ Ws1, const float* __restrict__ bs1,
    const float* __restrict__ Ws2, const float* __restrict__ bs2,
    const float* __restrict__ Wp1, const float* __restrict__ bp1,
    const float* __restrict__ Wp2, const float* __restrict__ bp2,
    const float* __restrict__ Wv1, const float* __restrict__ bv1,
    const float* __restrict__ Wv2, const float* __restrict__ bv2,
    float* __restrict__ out)
{
  const int b    = blockIdx.x;
  const int t    = threadIdx.x;   // 0..511
  const int lane = t & 63;
  const int wid  = t >> 6;        // 0..7

  // big layout: embedder = h tile [16][256] at [0..4095], emb_hi [256][33] at
  // [8448..16895] (pass 1), emb_lo [256][33] at [0..8447] (pass 2, post-h).
  // phase 3 overlays t1|sh|a1|v1 at [0..639].
  __shared__ __align__(16) float big[16896];
  __shared__ __align__(16) float we2_s[KS * E];    // 4 KB
  __shared__ int   id_l[NF];
  __shared__ __align__(16) float val_l[NF];
  __shared__ __align__(16) float w_s[NF];
  __shared__ __align__(16) float red_s[512];
  __shared__ int   wcnt[4];
  __shared__ float wred[8];
  __shared__ __align__(16) float qt_s[H];
  __shared__ float ct_s[H];
  __shared__ __align__(16) float att_s[E];
  __shared__ float v_scalar;

  // ---------------- phase 0: closed-form "argsort" ----------------
  int ai = 0, pin = 0;
  if (t < NF) {
    id_l[t] = 0; val_l[t] = 0.f;                   // tok >= L defaults
    ai = (acquired[b * NF + t] != 0) ? 1 : 0;
    const unsigned long long mask = __ballot(ai);
    pin = __popcll(mask & ((1ull << lane) - 1ull));
    if (lane == 0) wcnt[wid] = __popcll(mask);     // wid 0..3 here
  }
  if (t < H) { qt_s[t] = 0.f; ct_s[t] = 0.f; att_s[t] = 0.f; }
  __syncthreads();
  const int L = wcnt[0] + wcnt[1] + wcnt[2] + wcnt[3];
  if (t < NF && ai) {
    int pexcl = pin;
    #pragma unroll
    for (int w = 0; w < 4; ++w) if (w < wid) pexcl += wcnt[w];
    const int rank = L - pexcl - 1;                // # acquired with index > t
    id_l[rank]  = t + 1;
    val_l[rank] = state[b * NF + t];
  }
  __syncthreads();

  // ---------------- phase 1: embedder, two col-half passes ----------------
  const int pA   = t >> 8;                // step-A k-subrange (0/1)
  const int tokA = t & 255;               // step-A token
  const int idA  = id_l[tokA];
  const float vA = val_l[tokA];
  const float* __restrict__ w1r = We1 + idA * EH;
  const int tg4 = (t >> 3) * 4;           // step-B: 4 owned tokens
  const int cg4 = (t & 7) * 4;            // step-B: 4 owned cols (in half)

  for (int half = 1; half >= 0; --half) {
    float4 c0{0,0,0,0}, c1{0,0,0,0}, c2{0,0,0,0}, c3{0,0,0,0};
    for (int kt = 0; kt < EH / KS; ++kt) {
      {  // step A: h tile [16][256] into big[0..4095]
        const int kb = kt * KS + pA * 8;
        #pragma unroll
        for (int q = 0; q < 2; ++q) {
          const float4 wr = *(const float4*)(w1r + kb + q * 4);   // gather
          const float4 w0 = *(const float4*)(We1 + kb + q * 4);   // uniform
          const float4 bb = *(const float4*)(be1 + kb + q * 4);   // uniform
          const int r = (pA * 8 + q * 4) * NF + tokA;
          big[r]          = fmaxf(fmaf(vA, w0.x, wr.x) + bb.x, 0.f);
          big[r + NF]     = fmaxf(fmaf(vA, w0.y, wr.y) + bb.y, 0.f);
          big[r + 2*NF]   = fmaxf(fmaf(vA, w0.z, wr.z) + bb.z, 0.f);
          big[r + 3*NF]   = fmaxf(fmaf(vA, w0.w, wr.w) + bb.w, 0.f);
        }
        const int r2 = t >> 5, cc = (t & 31) * 2;  // we2 tile [16][64]
        we2_s[r2 * E + cc]     = We2[(kt * KS + r2) * E + cc];
        we2_s[r2 * E + cc + 1] = We2[(kt * KS + r2) * E + cc + 1];
      }
      __syncthreads();
      if (wid * 32 < L) {   // wave-uniform skip of fully-dead token waves
        #pragma unroll 2
        for (int k = 0; k < KS; ++k) {
          const float4 w2 = *(const float4*)&we2_s[k * E + half * 32 + cg4];
          const float4 hv = *(const float4*)&big[k * NF + tg4];
          c0 = f4ma(hv.x, w2, c0); c1 = f4ma(hv.y, w2, c1);
          c2 = f4ma(hv.z, w2, c2); c3 = f4ma(hv.w, w2, c3);
        }
      }
      __syncthreads();   // h tile consumed before overwrite / retire
    }
    {  // retire this col-half into emb LDS (scalar stores; tok>=L -> 0)
      const int colb = half * 32 + cg4;
      const float4 b2 = *(const float4*)(be2 + colb);
      float* __restrict__ dst = big + (half ? EHI : 0);
      #pragma unroll
      for (int r = 0; r < 4; ++r) {
        const float4 a = (r == 0) ? c0 : (r == 1) ? c1 : (r == 2) ? c2 : c3;
        const int tok = tg4 + r;
        const bool ok = tok < L;
        float* d = dst + tok * EPS + cg4;
        d[0] = ok ? a.x + b2.x : 0.f;
        d[1] = ok ? a.y + b2.y : 0.f;
        d[2] = ok ? a.z + b2.z : 0.f;
        d[3] = ok ? a.w + b2.w : 0.f;
      }
    }
    // no barrier needed between passes: pass-2 h writes touch [0..4095],
    // disjoint from emb_hi [8448..]; pass-2 step A syncs before step B.
  }
  __syncthreads();

  // ---------------- phase 2: attention + LSTM (emb in LDS halves) ---------
  if (L > 0) {
    const float invL = 1.f / (float)L;
    for (int it = 0; it < NSHUF; ++it) {
      if (it == 0) {
        // qt == 0 -> masked logits all 0 -> uniform softmax over first L
        if (t < NF) w_s[t] = (t < L) ? invL : 0.f;
        __syncthreads();
      } else {
        float lg = -1e30f;
        if (t < L) {
          float d0 = 0.f, d1 = 0.f, d2 = 0.f, d3 = 0.f;
          const float* __restrict__ el = big + t * EPS;
          const float* __restrict__ eh = big + EHI + t * EPS;
          #pragma unroll
          for (int j = 0; j < 32; j += 4) {
            const float4 ql = *(const float4*)(qt_s + j);
            const float4 qh = *(const float4*)(qt_s + 32 + j);
            d0 = fmaf(el[j],     ql.x, fmaf(eh[j],     qh.x, d0));
            d1 = fmaf(el[j + 1], ql.y, fmaf(eh[j + 1], qh.y, d1));
            d2 = fmaf(el[j + 2], ql.z, fmaf(eh[j + 2], qh.z, d2));
            d3 = fmaf(el[j + 3], ql.w, fmaf(eh[j + 3], qh.w, d3));
          }
          lg = (d0 + d1) + (d2 + d3);
        }
        float m = lg;
        #pragma unroll
        for (int d = 32; d > 0; d >>= 1) m = fmaxf(m, __shfl_xor(m, d));
        if (lane == 0 && wid < 4) wred[wid] = m;
        __syncthreads();
        m = fmaxf(fmaxf(wred[0], wred[1]), fmaxf(wred[2], wred[3]));
        const float pp = (t < L) ? __expf(lg - m) : 0.f;
        float s = pp;
        #pragma unroll
        for (int d = 32; d > 0; d >>= 1) s += __shfl_xor(s, d);
        if (lane == 0 && wid < 4) wred[4 + wid] = s;
        __syncthreads();
        s = (wred[4] + wred[5]) + (wred[6] + wred[7]);
        if (t < NF) w_s[t] = pp / s;
        __syncthreads();
      }

      // attended[col] = sum_tok w[tok]*emb[tok][col]; (col, token-group)
      {
        const int col = t & 63;
        if (wid * 32 < L) {
          const float* __restrict__ src = (col < 32)
              ? big + wid * 32 * EPS + col
              : big + EHI + wid * 32 * EPS + (col - 32);
          const float* __restrict__ wp = w_s + wid * 32;
          float s0 = 0.f, s1 = 0.f;
          #pragma unroll
          for (int i = 0; i < 32; i += 2) {
            s0 = fmaf(wp[i],     src[i * EPS],       s0);
            s1 = fmaf(wp[i + 1], src[(i + 1) * EPS], s1);
          }
          red_s[t] = s0 + s1;
        } else {
          red_s[t] = 0.f;
        }
      }
      __syncthreads();
      if (t < E) {
        float s0 = 0.f;
        #pragma unroll
        for (int q = 0; q < 8; ++q) s0 += red_s[q * 64 + t];
        att_s[t] = s0;
      }
      __syncthreads();

      // gates: waves 0-3: att@Wih, waves 4-7: qt@Whh (qt=0 at it0 -> 0)
      {
        const int col = t & 255;
        const int hf  = t >> 8;
        const float* __restrict__ W = hf ? Whh : Wih;
        const float* __restrict__ x = hf ? qt_s : att_s;
        float g0 = 0.f, g1 = 0.f, g2 = 0.f, g3 = 0.f;
        #pragma unroll
        for (int e = 0; e < 64; e += 4) {
          const float4 q = *(const float4*)(x + e);
          g0 = fmaf(q.x, W[(e)     * 256 + col], g0);
          g1 = fmaf(q.y, W[(e + 1) * 256 + col], g1);
          g2 = fmaf(q.z, W[(e + 2) * 256 + col], g2);
          g3 = fmaf(q.w, W[(e + 3) * 256 + col], g3);
        }
        red_s[t] = (g0 + g1) + (g2 + g3);
      }
      __syncthreads();
      if (t < 256) red_s[t] = red_s[t] + red_s[256 + t] + bih[t] + bhh[t];
      __syncthreads();
      if (t < H) {
        const float ig = red_s[t];
        const float fg = red_s[H + t];
        const float gg = red_s[2 * H + t];
        const float og = red_s[3 * H + t];
        float c = ct_s[t];
        c = fsig(fg) * c + fsig(ig) * ftanh(gg);
        ct_s[t] = c;
        qt_s[t] = fsig(og) * ftanh(c);
      }
      __syncthreads();
    }
  }

  // ---------------- phase 3: DuelingNet (overlays big) ----------------
  float* __restrict__ t1_s = big;          // 256
  float* __restrict__ sh_s = big + 256;    // 128
  float* __restrict__ a1_s = big + 384;    // 128
  float* __restrict__ v1_s = big + 512;    // 128
  {
    const int col = t & 255;
    const int hf  = t >> 8;
    const float* __restrict__ x = hf ? qt_s : att_s;
    const float* __restrict__ W = Ws1 + hf * 64 * SHD;
    float x0 = 0.f, x1 = 0.f, x2 = 0.f, x3 = 0.f;
    #pragma unroll
    for (int k = 0; k < 64; k += 4) {
      const float4 q = *(const float4*)(x + k);
      x0 = fmaf(q.x, W[(k)     * SHD + col], x0);
      x1 = fmaf(q.y, W[(k + 1) * SHD + col], x1);
      x2 = fmaf(q.z, W[(k + 2) * SHD + col], x2);
      x3 = fmaf(q.w, W[(k + 3) * SHD + col], x3);
    }
    red_s[t] = (x0 + x1) + (x2 + x3);
  }
  __syncthreads();
  if (t < SHD) t1_s[t] = fmaxf(red_s[t] + red_s[256 + t] + bs1[t], 0.f);
  __syncthreads();
  {
    const int col = t & 127;
    const int qq  = t >> 7;
    const float* __restrict__ xq = t1_s + qq * 64;
    float x0 = 0.f, x1 = 0.f, x2 = 0.f, x3 = 0.f;
    #pragma unroll
    for (int k = 0; k < 64; k += 4) {
      const float4 q = *(const float4*)(xq + k);
      x0 = fmaf(q.x, Ws2[(qq * 64 + k)     * SD + col], x0);
      x1 = fmaf(q.y, Ws2[(qq * 64 + k + 1) * SD + col], x1);
      x2 = fmaf(q.z, Ws2[(qq * 64 + k + 2) * SD + col], x2);
      x3 = fmaf(q.w, Ws2[(qq * 64 + k + 3) * SD + col], x3);
    }
    red_s[t] = (x0 + x1) + (x2 + x3);
  }
  __syncthreads();
  if (t < SD)
    sh_s[t] = fmaxf((red_s[t] + red_s[128 + t]) + (red_s[256 + t] + red_s[384 + t]) + bs2[t], 0.f);
  __syncthreads();
  {
    const int col  = t & 127;
    const int half = (t >> 7) & 1;
    const int net  = t >> 8;
    const float* __restrict__ W  = (net ? Wv1 : Wp1) + half * 64 * SD;
    const float* __restrict__ xh = sh_s + half * 64;
    float x0 = 0.f, x1 = 0.f, x2 = 0.f, x3 = 0.f;
    #pragma unroll
    for (int k = 0; k < 64; k += 4) {
      const float4 q = *(const float4*)(xh + k);
      x0 = fmaf(q.x, W[(k)     * SD + col], x0);
      x1 = fmaf(q.y, W[(k + 1) * SD + col], x1);
      x2 = fmaf(q.z, W[(k + 2) * SD + col], x2);
      x3 = fmaf(q.w, W[(k + 3) * SD + col], x3);
    }
    red_s[t] = (x0 + x1) + (x2 + x3);
  }
  __syncthreads();
  if (t < SD) {
    a1_s[t] = fmaxf(red_s[t] + red_s[128 + t] + bp1[t], 0.f);
  } else if (t < 2 * SD) {
    const int tt = t - SD;
    v1_s[tt] = fmaxf(red_s[256 + tt] + red_s[384 + tt] + bv1[tt], 0.f);
  }
  __syncthreads();
  if (wid == 7) {
    float vv = fmaf(v1_s[lane], Wv2[lane], v1_s[lane + 64] * Wv2[lane + 64]);
    #pragma unroll
    for (int d = 32; d > 0; d >>= 1) vv += __shfl_xor(vv, d);
    if (lane == 0) v_scalar = vv + bv2[0];
  }
  float adv = 0.f;
  if (t < NA) {
    float x0 = 0.f, x1 = 0.f, x2 = 0.f, x3 = 0.f;
    #pragma unroll
    for (int k = 0; k < SD; k += 4) {
      const float4 a = *(const float4*)(a1_s + k);
      x0 = fmaf(a.x, Wp2[(k)     * NA + t], x0);
      x1 = fmaf(a.y, Wp2[(k + 1) * NA + t], x1);
      x2 = fmaf(a.z, Wp2[(k + 2) * NA + t], x2);
      x3 = fmaf(a.w, Wp2[(k + 3) * NA + t], x3);
    }
    adv = bp2[t] + (x0 + x1) + (x2 + x3);
  }
  float ss = adv;                       // 0 for t >= NA
  #pragma unroll
  for (int d = 32; d > 0; d >>= 1) ss += __shfl_xor(ss, d);
  if (lane == 0) wred[wid] = ss;
  __syncthreads();
  const float mean = ((wred[0] + wred[1]) + (wred[2] + wred[3]) +
                      (wred[4] + wred[5]) + (wred[6] + wred[7])) * (1.f / (float)NA);
  if (t < NA) out[b * NA + t] = v_scalar + adv - mean;
}

}  // namespace

extern "C" void kernel_launch(void* const* d_in, const int* in_sizes, int n_in,
                              void* d_out, int out_size, void* d_ws, size_t ws_size,
                              hipStream_t stream) {
  const float* state    = (const float*)d_in[0];
  const int*   acquired = (const int*)d_in[1];
  const float* We1 = (const float*)d_in[2];
  const float* be1 = (const float*)d_in[3];
  const float* We2 = (const float*)d_in[4];
  const float* be2 = (const float*)d_in[5];
  const float* Wih = (const float*)d_in[6];
  const float* Whh = (const float*)d_in[7];
  const float* bih = (const float*)d_in[8];
  const float* bhh = (const float*)d_in[9];
  const float* Ws1 = (const float*)d_in[10];
  const float* bs1 = (const float*)d_in[11];
  const float* Ws2 = (const float*)d_in[12];
  const float* bs2 = (const float*)d_in[13];
  const float* Wp1 = (const float*)d_in[14];
  const float* bp1 = (const float*)d_in[15];
  const float* Wp2 = (const float*)d_in[16];
  const float* bp2 = (const float*)d_in[17];
  const float* Wv1 = (const float*)d_in[18];
  const float* bv1 = (const float*)d_in[19];
  const float* Wv2 = (const float*)d_in[20];
  const float* bv2 = (const float*)d_in[21];
  float* out = (float*)d_out;

  const int Bn = in_sizes[0] / NF;   // 2048
  hipLaunchKernelGGL(seqnet, dim3(Bn), dim3(512), 0, stream,
                     state, acquired, We1, be1, We2, be2, Wih, Whh, bih, bhh,
                     Ws1, bs1, Ws2, bs2, Wp1, bp1, Wp2, bp2, Wv1, bv1, Wv2, bv2,
                     out);
}

// Round 9
// 298.557 us; speedup vs baseline: 1.0999x; 1.0999x over previous
//
#include <hip/hip_runtime.h>
#include <math.h>

namespace {

constexpr int NF   = 256;   // n_feature / tokens
constexpr int EH   = 128;   // embedder hidden
constexpr int E    = 64;    // embedded dim
constexpr int EP   = 65;    // padded emb row stride (odd => conflict-free)
constexpr int H    = 64;    // lstm size
constexpr int SHD  = 256;   // shared hidden
constexpr int SD   = 128;   // shared dim
constexpr int NA   = 257;   // n_action
constexpr int NSHUF = 4;

__device__ __forceinline__ float fsig(float x) {
  return 1.f / (1.f + __expf(-x));
}
__device__ __forceinline__ float ftanh(float x) {
  return 1.f - 2.f / (__expf(2.f * x) + 1.f);
}
__device__ __forceinline__ float4 f4ma(float s, const float4 w, float4 a) {
  a.x = fmaf(s, w.x, a.x); a.y = fmaf(s, w.y, a.y);
  a.z = fmaf(s, w.z, a.z); a.w = fmaf(s, w.w, a.w);
  return a;
}

// Allocator model (r2-r8): it lands ONE occupancy tier below the declared
// cap. (256,4)/waves_per_eu(4) cap 128 -> got 64 + spill; no bound cap 512
// -> got 256. So declare (512,2): cap 256 -> predicted landing 128, which
// fits this kernel's ~80-reg live set with zero spill at 4 waves/SIMD.
__global__ __launch_bounds__(512, 2)
void seqnet(
    const float* __restrict__ state, const int* __restrict__ acquired,
    const float* __restrict__ We1, const float* __restrict__ be1,
    const float* __restrict__ We2, const float* __restrict__ be2,
    const float* __restrict__ Wih, const float* __restrict__ Whh,
    const float* __restrict__ bih, const float* __restrict__ bhh,
    const float* __restrict__ Ws1, const float* __restrict__ bs1,
    const float* __restrict__ Ws2, const float* __restrict__ bs2,
    const float* __restrict__ Wp1, const float* __restrict__ bp1,
    const float* __restrict__ Wp2, const float* __restrict__ bp2,
    const float* __restrict__ Wv1, const float* __restrict__ bv1,
    const float* __restrict__ Wv2, const float* __restrict__ bv2,
    float* __restrict__ out)
{
  const int b    = blockIdx.x;
  const int t    = threadIdx.x;   // 0..511
  const int lane = t & 63;
  const int wid  = t >> 6;        // 0..7

  // big: embedder phase = h_s[32][256] (32KB) | we2_s[32][64] (8KB);
  //      afterwards     = emb[256][EP] fp32 (66.56 KB).
  __shared__ __align__(16) float big[NF * EP];
  __shared__ int   id_l[NF];
  __shared__ __align__(16) float val_l[NF];
  __shared__ __align__(16) float w_s[NF];
  __shared__ __align__(16) float red_s[512];
  __shared__ __align__(16) float t1_s[SHD];
  __shared__ __align__(16) float sh_s[SD];
  __shared__ __align__(16) float a1_s[SD];
  __shared__ __align__(16) float v1_s[SD];
  __shared__ int   wcnt[4];
  __shared__ float wred[8];
  __shared__ __align__(16) float qt_s[H];
  __shared__ float ct_s[H];
  __shared__ __align__(16) float att_s[E];
  __shared__ float v_scalar;

  // ---------------- phase 0: closed-form "argsort" ----------------
  int ai = 0, pin = 0;
  if (t < NF) {
    id_l[t] = 0; val_l[t] = 0.f;                   // tok >= L defaults
    ai = (acquired[b * NF + t] != 0) ? 1 : 0;
    const unsigned long long mask = __ballot(ai);
    pin = __popcll(mask & ((1ull << lane) - 1ull));
    if (lane == 0) wcnt[wid] = __popcll(mask);     // wid 0..3 here
  }
  if (t < H) { qt_s[t] = 0.f; ct_s[t] = 0.f; att_s[t] = 0.f; }
  __syncthreads();
  const int L = wcnt[0] + wcnt[1] + wcnt[2] + wcnt[3];
  if (t < NF && ai) {
    int pexcl = pin;
    #pragma unroll
    for (int w = 0; w < 4; ++w) if (w < wid) pexcl += wcnt[w];
    const int rank = L - pexcl - 1;                // # acquired with index > t
    id_l[rank]  = t + 1;
    val_l[rank] = state[b * NF + t];
  }
  __syncthreads();

  // ---------------- phase 1: embedder as block GEMM ----------------
  float* __restrict__ h_s   = big;            // [32][256]
  float* __restrict__ we2_s = big + 32 * NF;  // [32][64]
  const int pA   = t >> 8;
  const int tokA = t & 255;
  const int idA  = id_l[tokA];
  const float vA = val_l[tokA];
  const float* __restrict__ w1r = We1 + idA * EH;
  const int tg8 = (t >> 4) * 8;               // 8 tokens owned in step B
  const int cg4 = (t & 15) * 4;               // 4 cols owned in step B

  float4 a0{0,0,0,0}, a1{0,0,0,0}, a2{0,0,0,0}, a3{0,0,0,0};
  float4 a4{0,0,0,0}, a5{0,0,0,0}, a6{0,0,0,0}, a7{0,0,0,0};

  for (int kt = 0; kt < 4; ++kt) {
    {  // step A: h K-tile [32][256] (all tokens: cheap, keeps h defined)
      const int kb = kt * 32 + pA * 16;
      #pragma unroll
      for (int q = 0; q < 4; ++q) {
        const float4 wr = *(const float4*)(w1r + kb + q * 4);   // gather
        const float4 w0 = *(const float4*)(We1 + kb + q * 4);   // uniform
        const float4 bb = *(const float4*)(be1 + kb + q * 4);   // uniform
        const int r = (pA * 16 + q * 4) * NF + tokA;
        h_s[r]          = fmaxf(fmaf(vA, w0.x, wr.x) + bb.x, 0.f);
        h_s[r + NF]     = fmaxf(fmaf(vA, w0.y, wr.y) + bb.y, 0.f);
        h_s[r + 2*NF]   = fmaxf(fmaf(vA, w0.z, wr.z) + bb.z, 0.f);
        h_s[r + 3*NF]   = fmaxf(fmaf(vA, w0.w, wr.w) + bb.w, 0.f);
      }
      const int r2 = t >> 4, c2 = (t & 15) * 4;
      *(float4*)&we2_s[r2 * E + c2] = *(const float4*)(We2 + (kt * 32 + r2) * E + c2);
    }
    __syncthreads();
    if (tg8 < L) {   // wave-mostly-uniform skip of dead tokens
      #pragma unroll 2
      for (int k = 0; k < 32; ++k) {
        const float4 w2 = *(const float4*)&we2_s[k * E + cg4];
        const float4 ha = *(const float4*)&h_s[k * NF + tg8];
        a0 = f4ma(ha.x, w2, a0); a1 = f4ma(ha.y, w2, a1);
        a2 = f4ma(ha.z, w2, a2); a3 = f4ma(ha.w, w2, a3);
        const float4 hb = *(const float4*)&h_s[k * NF + tg8 + 4];
        a4 = f4ma(hb.x, w2, a4); a5 = f4ma(hb.y, w2, a5);
        a6 = f4ma(hb.z, w2, a6); a7 = f4ma(hb.w, w2, a7);
      }
    }
    __syncthreads();   // protect h_s/we2_s overwrite (or emb overlay below)
  }
  {  // retire accumulators into padded LDS emb (scalar stores: no align UB)
    const float4 b2 = *(const float4*)(be2 + cg4);
    float* e0 = &big[tg8 * EP + cg4];
    e0[0]=a0.x+b2.x; e0[1]=a0.y+b2.y; e0[2]=a0.z+b2.z; e0[3]=a0.w+b2.w; e0+=EP;
    e0[0]=a1.x+b2.x; e0[1]=a1.y+b2.y; e0[2]=a1.z+b2.z; e0[3]=a1.w+b2.w; e0+=EP;
    e0[0]=a2.x+b2.x; e0[1]=a2.y+b2.y; e0[2]=a2.z+b2.z; e0[3]=a2.w+b2.w; e0+=EP;
    e0[0]=a3.x+b2.x; e0[1]=a3.y+b2.y; e0[2]=a3.z+b2.z; e0[3]=a3.w+b2.w; e0+=EP;
    e0[0]=a4.x+b2.x; e0[1]=a4.y+b2.y; e0[2]=a4.z+b2.z; e0[3]=a4.w+b2.w; e0+=EP;
    e0[0]=a5.x+b2.x; e0[1]=a5.y+b2.y; e0[2]=a5.z+b2.z; e0[3]=a5.w+b2.w; e0+=EP;
    e0[0]=a6.x+b2.x; e0[1]=a6.y+b2.y; e0[2]=a6.z+b2.z; e0[3]=a6.w+b2.w; e0+=EP;
    e0[0]=a7.x+b2.x; e0[1]=a7.y+b2.y; e0[2]=a7.z+b2.z; e0[3]=a7.w+b2.w;
  }
  __syncthreads();

  // ---------------- phase 2: attention + LSTM (emb in LDS) ----------------
  if (L > 0) {
    const float invL = 1.f / (float)L;
    for (int it = 0; it < NSHUF; ++it) {
      if (it == 0) {
        // qt == 0 -> masked logits all 0 -> uniform softmax over first L
        if (t < NF) w_s[t] = (t < L) ? invL : 0.f;
        __syncthreads();
      } else {
        float lg = -1e30f;
        if (t < L) {
          float d0 = 0.f, d1 = 0.f, d2 = 0.f, d3 = 0.f;
          const float* __restrict__ er = big + t * EP;
          #pragma unroll
          for (int j = 0; j < E; j += 4) {
            const float4 q = *(const float4*)(qt_s + j);
            d0 = fmaf(er[j],     q.x, d0);
            d1 = fmaf(er[j + 1], q.y, d1);
            d2 = fmaf(er[j + 2], q.z, d2);
            d3 = fmaf(er[j + 3], q.w, d3);
          }
          lg = (d0 + d1) + (d2 + d3);
        }
        float m = lg;
        #pragma unroll
        for (int d = 32; d > 0; d >>= 1) m = fmaxf(m, __shfl_xor(m, d));
        if (lane == 0 && wid < 4) wred[wid] = m;
        __syncthreads();
        m = fmaxf(fmaxf(wred[0], wred[1]), fmaxf(wred[2], wred[3]));
        const float pp = (t < L) ? __expf(lg - m) : 0.f;
        float s = pp;
        #pragma unroll
        for (int d = 32; d > 0; d >>= 1) s += __shfl_xor(s, d);
        if (lane == 0 && wid < 4) wred[4 + wid] = s;
        __syncthreads();
        s = (wred[4] + wred[5]) + (wred[6] + wred[7]);
        if (t < NF) w_s[t] = pp / s;
        __syncthreads();
      }

      // attended[col] = sum_tok w[tok]*emb[tok][col]; (col, token-group)
      {
        const int col = t & 63;               // token group = wid
        if (wid * 32 < L) {
          const float* __restrict__ ec = big + wid * 32 * EP + col;
          const float* __restrict__ wp = w_s + wid * 32;
          float c0 = 0.f, c1 = 0.f;
          #pragma unroll
          for (int i = 0; i < 32; i += 2) {
            c0 = fmaf(wp[i],     ec[i * EP],       c0);
            c1 = fmaf(wp[i + 1], ec[(i + 1) * EP], c1);
          }
          red_s[t] = c0 + c1;
        } else {
          red_s[t] = 0.f;
        }
      }
      __syncthreads();
      if (t < E) {
        float s0 = 0.f;
        #pragma unroll
        for (int q = 0; q < 8; ++q) s0 += red_s[q * 64 + t];
        att_s[t] = s0;
      }
      __syncthreads();

      // gates: waves 0-3: att@Wih, waves 4-7: qt@Whh (qt=0 at it0 -> 0)
      {
        const int col = t & 255;
        const int hf  = t >> 8;
        const float* __restrict__ W = hf ? Whh : Wih;
        const float* __restrict__ x = hf ? qt_s : att_s;
        float g0 = 0.f, g1 = 0.f, g2 = 0.f, g3 = 0.f;
        #pragma unroll
        for (int e = 0; e < 64; e += 4) {
          const float4 q = *(const float4*)(x + e);
          g0 = fmaf(q.x, W[(e)     * 256 + col], g0);
          g1 = fmaf(q.y, W[(e + 1) * 256 + col], g1);
          g2 = fmaf(q.z, W[(e + 2) * 256 + col], g2);
          g3 = fmaf(q.w, W[(e + 3) * 256 + col], g3);
        }
        red_s[t] = (g0 + g1) + (g2 + g3);
      }
      __syncthreads();
      if (t < 256) red_s[t] = red_s[t] + red_s[256 + t] + bih[t] + bhh[t];
      __syncthreads();
      if (t < H) {
        const float ig = red_s[t];
        const float fg = red_s[H + t];
        const float gg = red_s[2 * H + t];
        const float og = red_s[3 * H + t];
        float c = ct_s[t];
        c = fsig(fg) * c + fsig(ig) * ftanh(gg);
        ct_s[t] = c;
        qt_s[t] = fsig(og) * ftanh(c);
      }
      __syncthreads();
    }
  }

  // ---------------- phase 3: DuelingNet ----------------
  {
    const int col = t & 255;
    const int hf  = t >> 8;
    const float* __restrict__ x = hf ? qt_s : att_s;
    const float* __restrict__ W = Ws1 + hf * 64 * SHD;
    float x0 = 0.f, x1 = 0.f, x2 = 0.f, x3 = 0.f;
    #pragma unroll
    for (int k = 0; k < 64; k += 4) {
      const float4 q = *(const float4*)(x + k);
      x0 = fmaf(q.x, W[(k)     * SHD + col], x0);
      x1 = fmaf(q.y, W[(k + 1) * SHD + col], x1);
      x2 = fmaf(q.z, W[(k + 2) * SHD + col], x2);
      x3 = fmaf(q.w, W[(k + 3) * SHD + col], x3);
    }
    red_s[t] = (x0 + x1) + (x2 + x3);
  }
  __syncthreads();
  if (t < SHD) t1_s[t] = fmaxf(red_s[t] + red_s[256 + t] + bs1[t], 0.f);
  __syncthreads();
  {
    const int col = t & 127;
    const int qq  = t >> 7;
    const float* __restrict__ xq = t1_s + qq * 64;
    float x0 = 0.f, x1 = 0.f, x2 = 0.f, x3 = 0.f;
    #pragma unroll
    for (int k = 0; k < 64; k += 4) {
      const float4 q = *(const float4*)(xq + k);
      x0 = fmaf(q.x, Ws2[(qq * 64 + k)     * SD + col], x0);
      x1 = fmaf(q.y, Ws2[(qq * 64 + k + 1) * SD + col], x1);
      x2 = fmaf(q.z, Ws2[(qq * 64 + k + 2) * SD + col], x2);
      x3 = fmaf(q.w, Ws2[(qq * 64 + k + 3) * SD + col], x3);
    }
    red_s[t] = (x0 + x1) + (x2 + x3);
  }
  __syncthreads();
  if (t < SD)
    sh_s[t] = fmaxf((red_s[t] + red_s[128 + t]) + (red_s[256 + t] + red_s[384 + t]) + bs2[t], 0.f);
  __syncthreads();
  {
    const int col  = t & 127;
    const int half = (t >> 7) & 1;
    const int net  = t >> 8;
    const float* __restrict__ W  = (net ? Wv1 : Wp1) + half * 64 * SD;
    const float* __restrict__ xh = sh_s + half * 64;
    float x0 = 0.f, x1 = 0.f, x2 = 0.f, x3 = 0.f;
    #pragma unroll
    for (int k = 0; k < 64; k += 4) {
      const float4 q = *(const float4*)(xh + k);
      x0 = fmaf(q.x, W[(k)     * SD + col], x0);
      x1 = fmaf(q.y, W[(k + 1) * SD + col], x1);
      x2 = fmaf(q.z, W[(k + 2) * SD + col], x2);
      x3 = fmaf(q.w, W[(k + 3) * SD + col], x3);
    }
    red_s[t] = (x0 + x1) + (x2 + x3);
  }
  __syncthreads();
  if (t < SD) {
    a1_s[t] = fmaxf(red_s[t] + red_s[128 + t] + bp1[t], 0.f);
  } else if (t < 2 * SD) {
    const int tt = t - SD;
    v1_s[tt] = fmaxf(red_s[256 + tt] + red_s[384 + tt] + bv1[tt], 0.f);
  }
  __syncthreads();
  if (wid == 7) {
    float vv = fmaf(v1_s[lane], Wv2[lane], v1_s[lane + 64] * Wv2[lane + 64]);
    #pragma unroll
    for (int d = 32; d > 0; d >>= 1) vv += __shfl_xor(vv, d);
    if (lane == 0) v_scalar = vv + bv2[0];
  }
  float adv = 0.f;
  if (t < NA) {
    float x0 = 0.f, x1 = 0.f, x2 = 0.f, x3 = 0.f;
    #pragma unroll
    for (int k = 0; k < SD; k += 4) {
      const float4 a = *(const float4*)(a1_s + k);
      x0 = fmaf(a.x, Wp2[(k)     * NA + t], x0);
      x1 = fmaf(a.y, Wp2[(k + 1) * NA + t], x1);
      x2 = fmaf(a.z, Wp2[(k + 2) * NA + t], x2);
      x3 = fmaf(a.w, Wp2[(k + 3) * NA + t], x3);
    }
    adv = bp2[t] + (x0 + x1) + (x2 + x3);
  }
  float ss = adv;                       // 0 for t >= NA
  #pragma unroll
  for (int d = 32; d > 0; d >>= 1) ss += __shfl_xor(ss, d);
  if (lane == 0) wred[wid] = ss;
  __syncthreads();
  const float mean = ((wred[0] + wred[1]) + (wred[2] + wred[3]) +
                      (wred[4] + wred[5]) + (wred[6] + wred[7])) * (1.f / (float)NA);
  if (t < NA) out[b * NA + t] = v_scalar + adv - mean;
}

}  // namespace

extern "C" void kernel_launch(void* const* d_in, const int* in_sizes, int n_in,
                              void* d_out, int out_size, void* d_ws, size_t ws_size,
                              hipStream_t stream) {
  const float* state    = (const float*)d_in[0];
  const int*   acquired = (const int*)d_in[1];
  const float* We1 = (const float*)d_in[2];
  const float* be1 = (const float*)d_in[3];
  const float* We2 = (const float*)d_in[4];
  const float* be2 = (const float*)d_in[5];
  const float* Wih = (const float*)d_in[6];
  const float* Whh = (const float*)d_in[7];
  const float* bih = (const float*)d_in[8];
  const float* bhh = (const float*)d_in[9];
  const float* Ws1 = (const float*)d_in[10];
  const float* bs1 = (const float*)d_in[11];
  const float* Ws2 = (const float*)d_in[12];
  const float* bs2 = (const float*)d_in[13];
  const float* Wp1 = (const float*)d_in[14];
  const float* bp1 = (const float*)d_in[15];
  const float* Wp2 = (const float*)d_in[16];
  const float* bp2 = (const float*)d_in[17];
  const float* Wv1 = (const float*)d_in[18];
  const float* bv1 = (const float*)d_in[19];
  const float* Wv2 = (const float*)d_in[20];
  const float* bv2 = (const float*)d_in[21];
  float* out = (float*)d_out;

  const int Bn = in_sizes[0] / NF;   // 2048
  hipLaunchKernelGGL(seqnet, dim3(Bn), dim3(512), 0, stream,
                     state, acquired, We1, be1, We2, be2, Wih, Whh, bih, bhh,
                     Ws1, bs1, Ws2, bs2, Wp1, bp1, Wp2, bp2, Wv1, bv1, Wv2, bv2,
                     out);
}